// Round 1
// baseline (130.705 us; speedup 1.0000x reference)
//
#include <hip/hip_runtime.h>
#include <math.h>

#define NW    33          // window taps
#define B_    2
#define L_    4096
#define H_    8
#define E_    64
#define TILE  64          // queries per block
#define KROWS 128         // TILE + 64 (window reach ±32)
#define QSTR  68          // LDS row stride (floats): 16B-aligned, breaks bank conflicts
#define ASTR  34

__global__ __launch_bounds__(256, 2)
void lda_kernel(const float* __restrict__ Q, const float* __restrict__ K,
                const float* __restrict__ V, float* __restrict__ O) {
    __shared__ float Qs[TILE * QSTR];     // 17.0 KB
    __shared__ float Ks[KROWS * QSTR];    // 34.0 KB
    __shared__ float As[TILE * ASTR];     //  8.5 KB   (scores -> weights)

    const int tid  = threadIdx.x;
    const int lane = tid & 63;
    const int wave = tid >> 6;
    const int l0   = blockIdx.x * TILE;
    const int bh   = blockIdx.y;              // b*H + h
    const int b    = bh >> 3;
    const int h    = bh & 7;

    const size_t base      = ((size_t)(b * L_) * H_ + h) * E_;  // + l*rowStride + e
    const int    rowStride = H_ * E_;                           // 512 floats

    // ---- stage Q: 64 rows x 64 floats, coalesced float4 ----
    #pragma unroll
    for (int i = 0; i < 4; ++i) {
        int idx = tid + 256 * i;              // 0..1023
        int row = idx >> 4;
        int c4  = idx & 15;
        float4 v = *(const float4*)(Q + base + (size_t)(l0 + row) * rowStride + c4 * 4);
        *(float4*)&Qs[row * QSTR + c4 * 4] = v;
    }
    // ---- stage K: 128 rows, row r <- K[clip(l0-32+r)] ----
    #pragma unroll
    for (int i = 0; i < 8; ++i) {
        int idx = tid + 256 * i;              // 0..2047
        int row = idx >> 4;
        int c4  = idx & 15;
        int rg  = l0 - 32 + row;
        rg = rg < 0 ? 0 : (rg > L_ - 1 ? L_ - 1 : rg);
        float4 v = *(const float4*)(K + base + (size_t)rg * rowStride + c4 * 4);
        *(float4*)&Ks[row * QSTR + c4 * 4] = v;
    }
    __syncthreads();

    // ---- scores: lane = query l; wave owns w-slice [9*wave, 9*wave+9) ----
    {
        const int w_lo = wave * 9;
        float acc[9];
        #pragma unroll
        for (int i = 0; i < 9; ++i) acc[i] = 0.f;

        #pragma unroll 4
        for (int e4 = 0; e4 < 16; ++e4) {
            float4 q = *(const float4*)&Qs[lane * QSTR + e4 * 4];
            #pragma unroll
            for (int wi = 0; wi < 9; ++wi) {
                int w = w_lo + wi;
                if (w < NW) {                 // wave-uniform predicate
                    float4 k = *(const float4*)&Ks[(lane + 2 * w) * QSTR + e4 * 4];
                    acc[wi] += q.x * k.x + q.y * k.y + q.z * k.z + q.w * k.w;
                }
            }
        }
        #pragma unroll
        for (int wi = 0; wi < 9; ++wi) {
            int w = w_lo + wi;
            if (w < NW) As[lane * ASTR + w] = acc[wi] * 0.125f;  // 1/sqrt(64)
        }
    }
    __syncthreads();

    // ---- softmax over 33 taps, one thread per query ----
    if (tid < TILE) {
        const int l = tid;
        float s[NW];
        float m = -1e30f;
        #pragma unroll
        for (int w = 0; w < NW; ++w) { s[w] = As[l * ASTR + w]; m = fmaxf(m, s[w]); }
        float sum = 0.f;
        #pragma unroll
        for (int w = 0; w < NW; ++w) { s[w] = __expf(s[w] - m); sum += s[w]; }
        float inv = 1.f / sum;
        #pragma unroll
        for (int w = 0; w < NW; ++w) As[l * ASTR + w] = s[w] * inv;
    }
    __syncthreads();

    // ---- PV: lane = e; 4 queries (one per wave) per iteration; V from global ----
    for (int lg = 0; lg < 16; ++lg) {
        const int l = lg * 4 + wave;
        float acc = 0.f;
        #pragma unroll
        for (int w = 0; w < NW; ++w) {
            int rg = l0 + l + 2 * w - 32;
            rg = rg < 0 ? 0 : (rg > L_ - 1 ? L_ - 1 : rg);
            float a = As[l * ASTR + w];                       // wave-uniform broadcast
            float v = V[base + (size_t)rg * rowStride + lane]; // coalesced 256B row
            acc = fmaf(a, v, acc);
        }
        O[base + (size_t)(l0 + l) * rowStride + lane] = acc;
    }
}

extern "C" void kernel_launch(void* const* d_in, const int* in_sizes, int n_in,
                              void* d_out, int out_size, void* d_ws, size_t ws_size,
                              hipStream_t stream) {
    const float* Q = (const float*)d_in[0];
    const float* K = (const float*)d_in[1];
    const float* V = (const float*)d_in[2];
    float* O = (float*)d_out;

    dim3 grid(L_ / TILE, B_ * H_);
    dim3 block(256);
    lda_kernel<<<grid, block, 0, stream>>>(Q, K, V, O);
}

// Round 2
// 109.394 us; speedup vs baseline: 1.1948x; 1.1948x over previous
//
#include <hip/hip_runtime.h>
#include <hip/hip_bf16.h>
#include <math.h>

#define NW    33          // window taps
#define B_    2
#define L_    4096
#define H_    8
#define E_    64
#define TILE  64          // queries per block
#define KROWS 128         // TILE + 64 (window reach +/-32)
#define QSTR  72          // ushort stride (144B: 16B-aligned rows, 2-way-max banks)
#define KSTR  72
#define VSTR  64          // exact 128B rows + additive chunk swizzle
#define ASTR  33

__device__ __forceinline__ unsigned short f2bf(float f) {
    __hip_bfloat16 h = __float2bfloat16(f);
    return __builtin_bit_cast(unsigned short, h);
}
__device__ __forceinline__ float bflo(unsigned int u) {
    return __builtin_bit_cast(float, u << 16);
}
__device__ __forceinline__ float bfhi(unsigned int u) {
    return __builtin_bit_cast(float, u & 0xffff0000u);
}

// dot of 8 bf16 elements (packed 2-per-u32) accumulated into c
__device__ __forceinline__ float dot8(uint4 q, uint4 k, float c) {
#if defined(__has_builtin) && __has_builtin(__builtin_amdgcn_fdot2_f32_bf16)
    typedef __bf16 b2 __attribute__((ext_vector_type(2)));
    c = __builtin_amdgcn_fdot2_f32_bf16(__builtin_bit_cast(b2, q.x), __builtin_bit_cast(b2, k.x), c, false);
    c = __builtin_amdgcn_fdot2_f32_bf16(__builtin_bit_cast(b2, q.y), __builtin_bit_cast(b2, k.y), c, false);
    c = __builtin_amdgcn_fdot2_f32_bf16(__builtin_bit_cast(b2, q.z), __builtin_bit_cast(b2, k.z), c, false);
    c = __builtin_amdgcn_fdot2_f32_bf16(__builtin_bit_cast(b2, q.w), __builtin_bit_cast(b2, k.w), c, false);
#else
    c = fmaf(bflo(q.x), bflo(k.x), c); c = fmaf(bfhi(q.x), bfhi(k.x), c);
    c = fmaf(bflo(q.y), bflo(k.y), c); c = fmaf(bfhi(q.y), bfhi(k.y), c);
    c = fmaf(bflo(q.z), bflo(k.z), c); c = fmaf(bfhi(q.z), bfhi(k.z), c);
    c = fmaf(bflo(q.w), bflo(k.w), c); c = fmaf(bfhi(q.w), bfhi(k.w), c);
#endif
    return c;
}

__global__ __launch_bounds__(256, 3)
void lda_kernel(const float* __restrict__ Q, const float* __restrict__ K,
                const float* __restrict__ V, float* __restrict__ O) {
    __shared__ unsigned short Qs[TILE * QSTR];    //  9216 B
    __shared__ unsigned short Ks[KROWS * KSTR];   // 18432 B
    __shared__ unsigned short Vs[KROWS * VSTR];   // 16384 B (swizzled chunks)
    __shared__ float As[TILE * ASTR];             //  8448 B   -> 52480 B total, 3 blocks/CU

    const int tid  = threadIdx.x;
    const int lane = tid & 63;
    const int wave = tid >> 6;
    const int l0   = blockIdx.x * TILE;
    const int bh   = blockIdx.y;              // b*H + h
    const int b    = bh >> 3;
    const int h    = bh & 7;

    const size_t base      = ((size_t)(b * L_) * H_ + h) * E_;
    const int    rowStride = H_ * E_;         // 512 floats

    // ---- stage Q (bf16): 64 rows x 16 float4-chunks ----
    #pragma unroll
    for (int i = 0; i < 4; ++i) {
        int idx = tid + 256 * i;              // 0..1023
        int row = idx >> 4;
        int c4  = idx & 15;
        float4 v = *(const float4*)(Q + base + (size_t)(l0 + row) * rowStride + c4 * 4);
        uint2 p;
        p.x = (unsigned)f2bf(v.x) | ((unsigned)f2bf(v.y) << 16);
        p.y = (unsigned)f2bf(v.z) | ((unsigned)f2bf(v.w) << 16);
        *(uint2*)&Qs[row * QSTR + c4 * 4] = p;
    }
    // ---- stage K and V (bf16): 128 rows each, row r <- clip(l0-32+r) ----
    #pragma unroll
    for (int i = 0; i < 8; ++i) {
        int idx = tid + 256 * i;              // 0..2047
        int row = idx >> 4;
        int c4  = idx & 15;
        int rg  = l0 - 32 + row;
        rg = rg < 0 ? 0 : (rg > L_ - 1 ? L_ - 1 : rg);
        const size_t goff = base + (size_t)rg * rowStride + c4 * 4;

        float4 kv = *(const float4*)(K + goff);
        uint2 pk;
        pk.x = (unsigned)f2bf(kv.x) | ((unsigned)f2bf(kv.y) << 16);
        pk.y = (unsigned)f2bf(kv.z) | ((unsigned)f2bf(kv.w) << 16);
        *(uint2*)&Ks[row * KSTR + c4 * 4] = pk;

        float4 vv = *(const float4*)(V + goff);
        uint2 pv;
        pv.x = (unsigned)f2bf(vv.x) | ((unsigned)f2bf(vv.y) << 16);
        pv.y = (unsigned)f2bf(vv.z) | ((unsigned)f2bf(vv.w) << 16);
        int c4s = (c4 + 5 * row) & 15;        // additive bank swizzle
        *(uint2*)&Vs[row * VSTR + c4s * 4] = pv;
    }
    __syncthreads();

    // ---- scores: lane = query; wave owns taps [9*wave, 9*wave+9) ----
    {
        const int w_lo = wave * 9;
        float acc[9];
        #pragma unroll
        for (int i = 0; i < 9; ++i) acc[i] = 0.f;

        #pragma unroll
        for (int ch = 0; ch < 8; ++ch) {      // 8 bf16 per chunk
            uint4 q4 = *(const uint4*)&Qs[lane * QSTR + ch * 8];
            #pragma unroll
            for (int wi = 0; wi < 9; ++wi) {
                int w = w_lo + wi;
                if (w < NW) {                 // wave-uniform predicate
                    uint4 k4 = *(const uint4*)&Ks[(lane + 2 * w) * KSTR + ch * 8];
                    acc[wi] = dot8(q4, k4, acc[wi]);
                }
            }
        }
        #pragma unroll
        for (int wi = 0; wi < 9; ++wi) {
            int w = w_lo + wi;
            if (w < NW) As[lane * ASTR + w] = acc[wi] * 0.125f;   // 1/sqrt(64)
        }
    }
    __syncthreads();

    // ---- softmax over 33 taps, one thread per query ----
    if (tid < TILE) {
        const int l = tid;
        float s[NW];
        float m = -1e30f;
        #pragma unroll
        for (int w = 0; w < NW; ++w) { s[w] = As[l * ASTR + w]; m = fmaxf(m, s[w]); }
        float sum = 0.f;
        #pragma unroll
        for (int w = 0; w < NW; ++w) { s[w] = __expf(s[w] - m); sum += s[w]; }
        float inv = 1.f / sum;
        #pragma unroll
        for (int w = 0; w < NW; ++w) As[l * ASTR + w] = s[w] * inv;
    }
    __syncthreads();

    // ---- PV: 8 queries per wave-instr; lane = (g = lane>>3 query, c = lane&7 e-chunk) ----
    {
        const int g = lane >> 3;
        const int c = lane & 7;
        #pragma unroll
        for (int oct = 0; oct < 2; ++oct) {
            const int l = wave * 16 + oct * 8 + g;     // local query index
            float4 accA = {0.f, 0.f, 0.f, 0.f};        // elems c*4   .. c*4+3
            float4 accB = {0.f, 0.f, 0.f, 0.f};        // elems c*4+32.. c*4+35
            for (int w = 0; w < NW; ++w) {
                const int r = l + 2 * w;               // staged V row, 0..127
                float a = As[l * ASTR + w];            // 8-way broadcast read
                int ca = ((c     + 5 * r) & 15) * 4;
                int cb = ((c + 8 + 5 * r) & 15) * 4;
                uint2 va = *(const uint2*)&Vs[r * VSTR + ca];
                uint2 vb = *(const uint2*)&Vs[r * VSTR + cb];
                accA.x = fmaf(a, bflo(va.x), accA.x);
                accA.y = fmaf(a, bfhi(va.x), accA.y);
                accA.z = fmaf(a, bflo(va.y), accA.z);
                accA.w = fmaf(a, bfhi(va.y), accA.w);
                accB.x = fmaf(a, bflo(vb.x), accB.x);
                accB.y = fmaf(a, bfhi(vb.x), accB.y);
                accB.z = fmaf(a, bflo(vb.y), accB.z);
                accB.w = fmaf(a, bfhi(vb.y), accB.w);
            }
            float* orow = O + base + (size_t)(l0 + l) * rowStride;
            *(float4*)(orow + c * 4)      = accA;      // contiguous 128B per 8-lane group
            *(float4*)(orow + 32 + c * 4) = accB;
        }
    }
}

extern "C" void kernel_launch(void* const* d_in, const int* in_sizes, int n_in,
                              void* d_out, int out_size, void* d_ws, size_t ws_size,
                              hipStream_t stream) {
    const float* Q = (const float*)d_in[0];
    const float* K = (const float*)d_in[1];
    const float* V = (const float*)d_in[2];
    float* O = (float*)d_out;

    dim3 grid(L_ / TILE, B_ * H_);
    dim3 block(256);
    lda_kernel<<<grid, block, 0, stream>>>(Q, K, V, O);
}

// Round 3
// 97.003 us; speedup vs baseline: 1.3474x; 1.1277x over previous
//
#include <hip/hip_runtime.h>
#include <hip/hip_bf16.h>
#include <math.h>

#define B_    2
#define L_    4096
#define H_    8
#define E_    64
#define TILE  64          // queries per block
#define KROWS 128         // TILE + 64 halo
#define QSTR  72          // u16 stride for Qs  (144B = 36 dw == 4 mod 32: conflict-free b128)
#define KSTR  72
#define VTSTR 136         // u16 stride for Vt[e][r] (272B = 68 dw == 4 mod 32)
#define PSTR  136         // u16 stride for Ps[l][r]

using frag8 = __attribute__((ext_vector_type(8))) short;  // 8 x bf16 (4 VGPRs)
using fl4   = __attribute__((ext_vector_type(4))) float;  // MFMA C/D

__device__ __forceinline__ unsigned short f2bf(float f) {
    return __builtin_bit_cast(unsigned short, __float2bfloat16(f));
}

__global__ __launch_bounds__(256, 3)
void lda_kernel(const float* __restrict__ Q, const float* __restrict__ K,
                const float* __restrict__ V, float* __restrict__ O) {
    // U: first Qs (stride QSTR), later reused as Ps (stride PSTR, zero-filled band matrix)
    __shared__ unsigned short U[TILE * PSTR];       // 17408 B
    __shared__ unsigned short Ks[KROWS * KSTR];     // 18432 B
    __shared__ unsigned short Vt[E_ * VTSTR];       // 17408 B  -> 53248 B total, 3 blocks/CU

    const int tid  = threadIdx.x;
    const int lane = tid & 63;
    const int wave = tid >> 6;
    const int col  = lane & 15;
    const int quad = lane >> 4;
    const int l0   = blockIdx.x * TILE;
    const int bh   = blockIdx.y;
    const int b    = bh >> 3;
    const int h    = bh & 7;

    const size_t base = ((size_t)(b * L_) * H_ + h) * E_;
    const int    rs   = H_ * E_;                    // 512 floats per l-step

    // ---- stage Q -> U (bf16, stride QSTR): coalesced float4 ----
    #pragma unroll
    for (int i = 0; i < 4; ++i) {
        int idx = tid + 256 * i;                    // 0..1023 = 64 rows x 16 chunks
        int row = idx >> 4, c4 = idx & 15;
        float4 v = *(const float4*)(Q + base + (size_t)(l0 + row) * rs + c4 * 4);
        uint2 p;
        p.x = (unsigned)f2bf(v.x) | ((unsigned)f2bf(v.y) << 16);
        p.y = (unsigned)f2bf(v.z) | ((unsigned)f2bf(v.w) << 16);
        *(uint2*)&U[row * QSTR + c4 * 4] = p;
    }
    // ---- stage K -> Ks (bf16): 128 rows, clip folded in ----
    #pragma unroll
    for (int i = 0; i < 8; ++i) {
        int idx = tid + 256 * i;                    // 0..2047 = 128 rows x 16 chunks
        int row = idx >> 4, c4 = idx & 15;
        int rg  = l0 - 32 + row;
        rg = rg < 0 ? 0 : (rg > L_ - 1 ? L_ - 1 : rg);
        float4 v = *(const float4*)(K + base + (size_t)rg * rs + c4 * 4);
        uint2 p;
        p.x = (unsigned)f2bf(v.x) | ((unsigned)f2bf(v.y) << 16);
        p.y = (unsigned)f2bf(v.z) | ((unsigned)f2bf(v.w) << 16);
        *(uint2*)&Ks[row * KSTR + c4 * 4] = p;
    }
    // ---- stage V TRANSPOSED -> Vt[e][r]: coalesced row loads, b64 LDS writes ----
    #pragma unroll
    for (int p = 0; p < 8; ++p) {
        int rb = p * 16 + wave * 4;                 // 4 consecutive staged rows
        float a0, a1, a2, a3;
        {
            int rg = l0 - 32 + rb;     rg = rg < 0 ? 0 : (rg > L_-1 ? L_-1 : rg);
            a0 = V[base + (size_t)rg * rs + lane];
        }
        {
            int rg = l0 - 32 + rb + 1; rg = rg < 0 ? 0 : (rg > L_-1 ? L_-1 : rg);
            a1 = V[base + (size_t)rg * rs + lane];
        }
        {
            int rg = l0 - 32 + rb + 2; rg = rg < 0 ? 0 : (rg > L_-1 ? L_-1 : rg);
            a2 = V[base + (size_t)rg * rs + lane];
        }
        {
            int rg = l0 - 32 + rb + 3; rg = rg < 0 ? 0 : (rg > L_-1 ? L_-1 : rg);
            a3 = V[base + (size_t)rg * rs + lane];
        }
        uint2 u;
        u.x = (unsigned)f2bf(a0) | ((unsigned)f2bf(a1) << 16);
        u.y = (unsigned)f2bf(a2) | ((unsigned)f2bf(a3) << 16);
        *(uint2*)&Vt[lane * VTSTR + rb] = u;        // e = lane, cols rb..rb+3
    }
    __syncthreads();   // B0

    // ---- score MFMA: wave owns rows [16w,16w+16), n-tiles nt = w..w+4 ----
    frag8 aq[2];
    #pragma unroll
    for (int k = 0; k < 2; ++k)
        aq[k] = *(const frag8*)&U[(wave * 16 + col) * QSTR + k * 32 + quad * 8];

    fl4 S[5];
    #pragma unroll
    for (int t = 0; t < 5; ++t) {
        int nt = wave + t;
        fl4 c = {0.f, 0.f, 0.f, 0.f};
        #pragma unroll
        for (int k = 0; k < 2; ++k) {
            frag8 bk = *(const frag8*)&Ks[(nt * 16 + col) * KSTR + k * 32 + quad * 8];
            c = __builtin_amdgcn_mfma_f32_16x16x32_bf16(aq[k], bk, c, 0, 0, 0);
        }
        S[t] = c;
    }

    // ---- in-wave softmax: row l = 16w + 4*quad + reg; r = 16(w+t) + col ----
    // d = r - l = 16t + col - 4*quad - reg; in-band iff 0<=d<=64 and d even.
    float pv[5][4];
    #pragma unroll
    for (int reg = 0; reg < 4; ++reg) {
        float mx = -1e30f;
        #pragma unroll
        for (int t = 0; t < 5; ++t) {
            int d = t * 16 + col - quad * 4 - reg;
            bool ib = (d >= 0) && (d <= 64) && ((d & 1) == 0);
            float sv = S[t][reg] * 0.125f;           // 1/sqrt(64)
            if (ib) mx = fmaxf(mx, sv);
        }
        #pragma unroll
        for (int m = 1; m < 16; m <<= 1) mx = fmaxf(mx, __shfl_xor(mx, m));
        float sum = 0.f;
        #pragma unroll
        for (int t = 0; t < 5; ++t) {
            int d = t * 16 + col - quad * 4 - reg;
            bool ib = (d >= 0) && (d <= 64) && ((d & 1) == 0);
            float e = ib ? __expf(S[t][reg] * 0.125f - mx) : 0.f;
            pv[t][reg] = e;
            sum += e;
        }
        #pragma unroll
        for (int m = 1; m < 16; m <<= 1) sum += __shfl_xor(sum, m);
        float inv = 1.f / sum;
        #pragma unroll
        for (int t = 0; t < 5; ++t) pv[t][reg] *= inv;
    }
    __syncthreads();   // B1: Qs dead, safe to overwrite U with Ps

    // ---- zero-fill Ps (64 x PSTR u16) with uint4 stores ----
    #pragma unroll
    for (int i = 0; i < 5; ++i) {
        int idx = tid + 256 * i;
        if (idx < (TILE * PSTR) / 8) {
            uint4 z = {0u, 0u, 0u, 0u};
            *(uint4*)&U[idx * 8] = z;
        }
    }
    __syncthreads();   // B2

    // ---- scatter in-band P (bf16) into Ps[l][r] ----
    #pragma unroll
    for (int reg = 0; reg < 4; ++reg) {
        int l = wave * 16 + quad * 4 + reg;
        #pragma unroll
        for (int t = 0; t < 5; ++t) {
            int r = (wave + t) * 16 + col;
            int d = r - l;
            if ((d >= 0) && (d <= 64) && ((d & 1) == 0))
                U[l * PSTR + r] = f2bf(pv[t][reg]);
        }
    }
    __syncthreads();   // B3

    // ---- PV MFMA: O[l][e] = sum_r P[l][r] V[r][e]; B-frags from Vt ----
    frag8 ap[4];
    #pragma unroll
    for (int k = 0; k < 4; ++k)
        ap[k] = *(const frag8*)&U[(wave * 16 + col) * PSTR + k * 32 + quad * 8];

    #pragma unroll
    for (int nt = 0; nt < 4; ++nt) {
        fl4 c = {0.f, 0.f, 0.f, 0.f};
        #pragma unroll
        for (int k = 0; k < 4; ++k) {
            frag8 bv = *(const frag8*)&Vt[(nt * 16 + col) * VTSTR + k * 32 + quad * 8];
            c = __builtin_amdgcn_mfma_f32_16x16x32_bf16(ap[k], bv, c, 0, 0, 0);
        }
        #pragma unroll
        for (int reg = 0; reg < 4; ++reg) {
            int l = wave * 16 + quad * 4 + reg;
            O[base + (size_t)(l0 + l) * rs + nt * 16 + col] = c[reg];
        }
    }
}

extern "C" void kernel_launch(void* const* d_in, const int* in_sizes, int n_in,
                              void* d_out, int out_size, void* d_ws, size_t ws_size,
                              hipStream_t stream) {
    const float* Q = (const float*)d_in[0];
    const float* K = (const float*)d_in[1];
    const float* V = (const float*)d_in[2];
    float* O = (float*)d_out;

    dim3 grid(L_ / TILE, B_ * H_);
    dim3 block(256);
    lda_kernel<<<grid, block, 0, stream>>>(Q, K, V, O);
}

// Round 4
// 95.669 us; speedup vs baseline: 1.3662x; 1.0140x over previous
//
#include <hip/hip_runtime.h>
#include <hip/hip_bf16.h>
#include <math.h>

#define B_    2
#define L_    4096
#define H_    8
#define E_    64
#define VTSTR 136        // u16 stride for Vt[e][parity*64 + rhat] (272B rows, 16B-aligned)
#define PSTR  72         // u16 stride for wave-private P rows (144B, 16B-aligned)

using frag8 = __attribute__((ext_vector_type(8))) short;  // 8 x bf16 (4 VGPRs)
using fl4   = __attribute__((ext_vector_type(4))) float;  // MFMA C/D

__device__ __forceinline__ unsigned short f2bf(float f) {
    return __builtin_bit_cast(unsigned short, __float2bfloat16(f));
}
__device__ __forceinline__ frag8 pack8(float4 a, float4 b) {
    frag8 r;
    r[0] = (short)f2bf(a.x); r[1] = (short)f2bf(a.y);
    r[2] = (short)f2bf(a.z); r[3] = (short)f2bf(a.w);
    r[4] = (short)f2bf(b.x); r[5] = (short)f2bf(b.y);
    r[6] = (short)f2bf(b.z); r[7] = (short)f2bf(b.w);
    return r;
}

__global__ __launch_bounds__(256, 4)
void lda_kernel(const float* __restrict__ Q, const float* __restrict__ K,
                const float* __restrict__ V, float* __restrict__ O) {
    __shared__ unsigned short Vt[E_ * VTSTR];        // 17408 B  (V transposed, parity-major)
    __shared__ unsigned short Pw[4 * 16 * PSTR];     //  9216 B  (wave-private band P) -> 26624 B

    const int tid  = threadIdx.x;
    const int lane = tid & 63;
    const int wave = tid >> 6;
    const int col  = lane & 15;
    const int quad = lane >> 4;
    const int p    = wave & 1;       // query parity this wave owns
    const int t    = wave >> 1;      // lhat tile (0 or 1): lhat in [16t, 16t+16)
    const int l0   = blockIdx.x * 64;
    const int bh   = blockIdx.y;
    const int b    = bh >> 3;
    const int h    = bh & 7;

    const size_t base = ((size_t)(b * L_) * H_ + h) * E_;
    const int    rs   = H_ * E_;     // 512 floats per l-step

    // ---- V staging: transpose into Vt[e][pg*64 + rhat]; staged row r = 2*rhat + pg ----
    #pragma unroll
    for (int i = 0; i < 8; ++i) {
        int g   = wave * 8 + i;       // 0..31
        int pg  = g >> 4;             // staged-row parity
        int rh0 = (g & 15) * 4;       // rhat base (4 consecutive rhat per write)
        float a0, a1, a2, a3;
        {
            int rg = l0 - 32 + 2 * (rh0 + 0) + pg; rg = rg < 0 ? 0 : (rg > L_-1 ? L_-1 : rg);
            a0 = V[base + (size_t)rg * rs + lane];
        }
        {
            int rg = l0 - 32 + 2 * (rh0 + 1) + pg; rg = rg < 0 ? 0 : (rg > L_-1 ? L_-1 : rg);
            a1 = V[base + (size_t)rg * rs + lane];
        }
        {
            int rg = l0 - 32 + 2 * (rh0 + 2) + pg; rg = rg < 0 ? 0 : (rg > L_-1 ? L_-1 : rg);
            a2 = V[base + (size_t)rg * rs + lane];
        }
        {
            int rg = l0 - 32 + 2 * (rh0 + 3) + pg; rg = rg < 0 ? 0 : (rg > L_-1 ? L_-1 : rg);
            a3 = V[base + (size_t)rg * rs + lane];
        }
        uint2 u;
        u.x = (unsigned)f2bf(a0) | ((unsigned)f2bf(a1) << 16);
        u.y = (unsigned)f2bf(a2) | ((unsigned)f2bf(a3) << 16);
        *(uint2*)&Vt[lane * VTSTR + pg * 64 + rh0] = u;   // e = lane
    }

    // ---- Q A-frags direct from global (query l = 2*(16t+col)+p, elems quad*8..+7 per k) ----
    const int lq = l0 + 2 * (16 * t + col) + p;
    frag8 aq[2];
    #pragma unroll
    for (int k = 0; k < 2; ++k) {
        const float* qp = Q + base + (size_t)lq * rs + k * 32 + quad * 8;
        aq[k] = pack8(*(const float4*)qp, *(const float4*)(qp + 4));
    }

    // ---- scores: 3 rhat-tiles (band [lhat, lhat+32] within rhat [16t, 16t+48)) ----
    fl4 S[3];
    #pragma unroll
    for (int c = 0; c < 3; ++c) {
        int rhat = 16 * (t + c) + col;           // key half-index for this lane's n
        int rg = l0 - 32 + 2 * rhat + p;
        rg = rg < 0 ? 0 : (rg > L_ - 1 ? L_ - 1 : rg);
        const float* kp = K + base + (size_t)rg * rs;
        fl4 acc = {0.f, 0.f, 0.f, 0.f};
        #pragma unroll
        for (int k = 0; k < 2; ++k) {
            frag8 bk = pack8(*(const float4*)(kp + k * 32 + quad * 8),
                             *(const float4*)(kp + k * 32 + quad * 8 + 4));
            acc = __builtin_amdgcn_mfma_f32_16x16x32_bf16(aq[k], bk, acc, 0, 0, 0);
        }
        S[c] = acc;
    }

    // ---- softmax fully in-register: row m = quad*4+reg lives on the 16 lanes of this quad ----
    float pw[3][4];
    #pragma unroll
    for (int reg = 0; reg < 4; ++reg) {
        int off = quad * 4 + reg;                // lhat local offset within tile
        float mx = -1e30f;
        #pragma unroll
        for (int c = 0; c < 3; ++c) {
            int j = 16 * c + col - off;          // tap index 0..32
            if (j >= 0 && j <= 32) mx = fmaxf(mx, S[c][reg] * 0.125f);
        }
        #pragma unroll
        for (int m = 1; m < 16; m <<= 1) mx = fmaxf(mx, __shfl_xor(mx, m));
        float sum = 0.f;
        #pragma unroll
        for (int c = 0; c < 3; ++c) {
            int j = 16 * c + col - off;
            float e = (j >= 0 && j <= 32) ? __expf(S[c][reg] * 0.125f - mx) : 0.f;
            pw[c][reg] = e; sum += e;
        }
        #pragma unroll
        for (int m = 1; m < 16; m <<= 1) sum += __shfl_xor(sum, m);
        float inv = 1.f / sum;
        #pragma unroll
        for (int c = 0; c < 3; ++c) pw[c][reg] *= inv;
    }

    // ---- zero + scatter P into wave-private region (no barrier: same-wave LDS order) ----
    const int pb = wave * 16 * PSTR;
    #pragma unroll
    for (int i = 0; i < 3; ++i) {
        int idx = lane + 64 * i;                 // 144 uint4 cover 16*72 u16
        if (idx < 144) { uint4 z = {0u,0u,0u,0u}; *(uint4*)&Pw[pb + idx * 8] = z; }
    }
    #pragma unroll
    for (int reg = 0; reg < 4; ++reg) {
        int off = quad * 4 + reg;
        #pragma unroll
        for (int c = 0; c < 3; ++c) {
            int j = 16 * c + col - off;
            if (j >= 0 && j <= 32)
                Pw[pb + off * PSTR + 16 * (t + c) + col] = f2bf(pw[c][reg]);
        }
    }

    // ---- P A-frags (k = rhat 0..63, zeros outside band) ----
    frag8 ap[2];
    #pragma unroll
    for (int k = 0; k < 2; ++k)
        ap[k] = *(const frag8*)&Pw[pb + col * PSTR + k * 32 + quad * 8];

    __syncthreads();   // the ONE barrier: Vt ready (V latency hidden under score+softmax)

    // ---- PV MFMA: O[l][e] = sum_rhat P[lhat][rhat] * V[2rhat+p][e] ----
    #pragma unroll
    for (int nt = 0; nt < 4; ++nt) {
        fl4 c = {0.f, 0.f, 0.f, 0.f};
        #pragma unroll
        for (int k = 0; k < 2; ++k) {
            frag8 bv = *(const frag8*)&Vt[(nt * 16 + col) * VTSTR + p * 64 + k * 32 + quad * 8];
            c = __builtin_amdgcn_mfma_f32_16x16x32_bf16(ap[k], bv, c, 0, 0, 0);
        }
        #pragma unroll
        for (int reg = 0; reg < 4; ++reg) {
            int l = 2 * (16 * t + quad * 4 + reg) + p;
            O[base + (size_t)(l0 + l) * rs + nt * 16 + col] = c[reg];
        }
    }
}

extern "C" void kernel_launch(void* const* d_in, const int* in_sizes, int n_in,
                              void* d_out, int out_size, void* d_ws, size_t ws_size,
                              hipStream_t stream) {
    const float* Q = (const float*)d_in[0];
    const float* K = (const float*)d_in[1];
    const float* V = (const float*)d_in[2];
    float* O = (float*)d_out;

    dim3 grid(L_ / 64, B_ * H_);
    dim3 block(256);
    lda_kernel<<<grid, block, 0, stream>>>(Q, K, V, O);
}